// Round 7
// baseline (240.006 us; speedup 1.0000x reference)
//
#include <hip/hip_runtime.h>
#include <math.h>

// Chamfer k-NN (k=16, L2), R20: fused binsort+pack, persistent work-queue
// scan, 3rd tau-merge, OOB p-advance fix.
// R19 post-mortem: 9300 VALU-inst/wave measured vs ~3000 modeled. Causes:
// (1) probe tau0 is a thin-slab (quasi-2D) 16th ~ 3x true r16^2 -> ~88
//     post-probe enqueues/query -> ballot-drain storm. Now tauLeft=3.
// (2) grid == residency (no backfill) + x-density-correlated block cost ->
//     33% occupancy is mostly finished-wave idle. Now: 1-wave persistent
//     blocks fetch 4-query chunks from per-set atomic queues.
// (3) ~60us fixed overhead: pack fused into binsort (per-set ranges found
//     in-block -> no global minmax, no memsets, no staging arrays).
// Also: dead lanes no longer advance p (was a latent OOB read).
// Pipeline: binsort_fused (4 blocks; zeroes out + queue ctrs; per-set
// counting sort + guards + header {xmin,sc,w}) -> scan (persistent).

#define INFV    3.0e38f
#define QDEPTH  16
#define NB      512
#define GUARD   320

__device__ __forceinline__ void ce(float& a, float& b) {
    float lo = fminf(a, b);
    b = fmaxf(a, b);
    a = lo;
}

// bitonic merge-sort of a bitonic 16-seq (stages 8,4,2,1 = 32 CE), ascending
__device__ __forceinline__ void bitonic16(float (&s)[16]) {
    ce(s[0],s[8]);  ce(s[1],s[9]);  ce(s[2],s[10]); ce(s[3],s[11]);
    ce(s[4],s[12]); ce(s[5],s[13]); ce(s[6],s[14]); ce(s[7],s[15]);
    ce(s[0],s[4]);  ce(s[1],s[5]);  ce(s[2],s[6]);  ce(s[3],s[7]);
    ce(s[8],s[12]); ce(s[9],s[13]); ce(s[10],s[14]);ce(s[11],s[15]);
    ce(s[0],s[2]);  ce(s[1],s[3]);  ce(s[4],s[6]);  ce(s[5],s[7]);
    ce(s[8],s[10]); ce(s[9],s[11]); ce(s[12],s[14]);ce(s[13],s[15]);
    ce(s[0],s[1]);  ce(s[2],s[3]);  ce(s[4],s[5]);  ce(s[6],s[7]);
    ce(s[8],s[9]);  ce(s[10],s[11]);ce(s[12],s[13]);ce(s[14],s[15]);
}

// Merge up to 8 queued values (qb[(base+i)*64], i<cnt-base) into sorted s[16].
__device__ __forceinline__ void drain_batch(float (&s)[16], const float* qb,
                                            int base, int cnt)
{
    float q[8];
#pragma unroll
    for (int i = 0; i < 8; ++i) {
        float v = qb[(base + i) * 64];
        q[i] = (base + i < cnt) ? v : INFV;
    }
    // sort8 ascending -- Batcher odd-even, 19 CE
    ce(q[0],q[1]); ce(q[2],q[3]); ce(q[4],q[5]); ce(q[6],q[7]);
    ce(q[0],q[2]); ce(q[1],q[3]); ce(q[4],q[6]); ce(q[5],q[7]);
    ce(q[1],q[2]); ce(q[5],q[6]);
    ce(q[0],q[4]); ce(q[1],q[5]); ce(q[2],q[6]); ce(q[3],q[7]);
    ce(q[2],q[4]); ce(q[3],q[5]);
    ce(q[1],q[2]); ce(q[3],q[4]); ce(q[5],q[6]);
    // bitonic halver vs sorted s[16]
#pragma unroll
    for (int i = 0; i < 8; ++i) s[8 + i] = fminf(s[8 + i], q[7 - i]);
    bitonic16(s);
}

__device__ __forceinline__ int binof(float x, float xmin, float sc) {
    int bn = (int)((x - xmin) * sc);
    return bn < 0 ? 0 : (bn > NB - 1 ? NB - 1 : bn);
}

// Fused pack + counting-sort. blockIdx.x: 0=pred b0, 1=pred b1, 2=tgt b0,
// 3=tgt b1. Per-set x-range found in-block (LDS reduce) -> per-set bins.
// Destination layout per set: [GUARD front | n data | GUARD back].
// Also zeroes out[0] and the scan's 4 chunk-queue counters.
__global__ __launch_bounds__(1024) void binsort_kernel(
    const float* __restrict__ src, const float* __restrict__ tgt,
    const float* __restrict__ flow,
    float4* __restrict__ ps4, float4* __restrict__ ts4,
    int* __restrict__ goffs, float* __restrict__ hdr,
    int* __restrict__ ctr, float* __restrict__ out, int N, int M)
{
    const int a = blockIdx.x, tid = threadIdx.x;
    const int n = (a < 2) ? N : M;
    const float* P0 = (a < 2) ? src + (size_t)a * N * 3
                              : tgt + (size_t)(a - 2) * M * 3;
    const float* F0 = (a < 2) ? flow + (size_t)a * N * 3 : (const float*)0;
    float4* dst = (a < 2) ? ps4 + (size_t)a * (N + 2 * GUARD)
                          : ts4 + (size_t)(a - 2) * (M + 2 * GUARD);

    if (tid == 0) { ctr[a] = 0; if (a == 0) out[0] = 0.0f; }

    // guard pads: x=+-1e30 kills the act-chain once rtau is finite; w=INFV
    // makes cd round to exactly INFV -> never enqueued even under tau=INFV.
    for (int i = tid; i < GUARD; i += 1024) {
        dst[i] = make_float4(-1e30f, 0.f, 0.f, INFV);
        dst[GUARD + n + i] = make_float4(1e30f, 0.f, 0.f, INFV);
    }

    // per-set x min/max
    float lmin = INFV, lmax = -INFV;
    for (int i = tid; i < n; i += 1024) {
        float x = P0[3 * i];
        if (a < 2) x += F0[3 * i];
        lmin = fminf(lmin, x); lmax = fmaxf(lmax, x);
    }
#pragma unroll
    for (int off = 32; off > 0; off >>= 1) {
        lmin = fminf(lmin, __shfl_down(lmin, off));
        lmax = fmaxf(lmax, __shfl_down(lmax, off));
    }
    __shared__ float rmin[16], rmax[16];
    __shared__ float sxmin, ssc;
    __shared__ int hist[NB];
    __shared__ int offs[NB + 1];
    __shared__ int cur[NB];
    if ((tid & 63) == 0) { rmin[tid >> 6] = lmin; rmax[tid >> 6] = lmax; }
    if (tid < NB) { hist[tid] = 0; cur[tid] = 0; }
    __syncthreads();
    if (tid == 0) {
        float mn = rmin[0], mx = rmax[0];
#pragma unroll
        for (int i = 1; i < 16; ++i) {
            mn = fminf(mn, rmin[i]); mx = fmaxf(mx, rmax[i]);
        }
        float range = mx - mn;
        float sc = (range > 0.f) ? (float)NB / range : 0.f;
        float w  = (range > 0.f) ? range * (1.0f / NB) : INFV;
        sxmin = mn; ssc = sc;
        hdr[a * 4 + 0] = mn; hdr[a * 4 + 1] = sc; hdr[a * 4 + 2] = w;
    }
    __syncthreads();
    const float xmin = sxmin, sc = ssc;

    for (int i = tid; i < n; i += 1024) {
        float x = P0[3 * i];
        if (a < 2) x += F0[3 * i];
        atomicAdd(&hist[binof(x, xmin, sc)], 1);
    }
    __syncthreads();
    // single-wave prefix scan over NB=512 bins: 8 bins/lane serial prefix,
    // then 64-lane shfl_up exclusive scan of lane totals.
    if (tid < 64) {
        const int base = tid * 8;
        int inc[8];
        int run = 0;
#pragma unroll
        for (int i = 0; i < 8; ++i) { run += hist[base + i]; inc[i] = run; }
        int x = run;
#pragma unroll
        for (int off = 1; off < 64; off <<= 1) {
            int y = __shfl_up(x, off);
            if (tid >= (unsigned)off) x += y;
        }
        const int excl = x - run;
#pragma unroll
        for (int i = 0; i < 8; ++i) offs[base + 1 + i] = excl + inc[i];
        if (tid == 0) offs[0] = 0;
    }
    __syncthreads();
    for (int i = tid; i < n; i += 1024) {
        float x = P0[3 * i], y = P0[3 * i + 1], z = P0[3 * i + 2];
        if (a < 2) { x += F0[3 * i]; y += F0[3 * i + 1]; z += F0[3 * i + 2]; }
        int bn = binof(x, xmin, sc);
        int slot = atomicAdd(&cur[bn], 1);
        dst[GUARD + offs[bn] + slot] =
            make_float4(x, y, z, fmaf(x, x, fmaf(y, y, z * z)));
    }
    if (tid <= NB) goffs[a * (NB + 1) + tid] = offs[tid];
}

// persistent 1-wave blocks; each fetches 4-query chunks from its set's
// atomic queue; 16 lanes/query (stride 16). blockIdx.y = set z.
__global__ __launch_bounds__(64, 4) void scan_kernel(
    const float4* __restrict__ ps4, const float4* __restrict__ ts4,
    const int* __restrict__ goffs, const float* __restrict__ hdr,
    int* __restrict__ ctr, float* __restrict__ out,
    int N, int M, float scale_out)
{
    __shared__ float qbuf[QDEPTH * 64];    // 4 KB per-lane queues, stride 64

    const int tid = threadIdx.x;
    const int z = blockIdx.y, b = z >> 1, dir = z & 1;
    const int nq = dir ? M : N;
    const int SN = N + 2 * GUARD, SM = M + 2 * GUARD;
    const float4* Qb = dir ? (ts4 + (size_t)b * SM) : (ps4 + (size_t)b * SN);
    const float4* R  = dir ? (ps4 + (size_t)b * SN) : (ts4 + (size_t)b * SM);
    const int oid = dir ? b : 2 + b;       // set id of the REF array
    const float xmin = hdr[oid * 4 + 0];
    const float sc   = hdr[oid * 4 + 1];
    const float w    = hdr[oid * 4 + 2];
    const int nch = (nq + 3) >> 2;
    const int l = tid & 15;                // lane within 16-lane group
    const float* qb_tid = qbuf + tid;

    float accTot = 0.0f;                   // per-lane across chunks

    for (;;) {
        int c;
        if (tid == 0) c = atomicAdd(&ctr[z], 1);
        c = __shfl(c, 0);
        if (c >= nch) break;

        const int qidx = c * 4 + (tid >> 4);
        const bool qv = qidx < nq;
        float4 q = Qb[GUARD + (qv ? qidx : 0)];
        const float qx = q.x, q2 = q.w;
        const float nx = -2.f * q.x, ny = -2.f * q.y, nz = -2.f * q.z;
        const int start = GUARD + goffs[oid * (NB + 1) + binof(qx, xmin, sc)];

        float s[16];
#pragma unroll
        for (int i = 0; i < 16; ++i) s[i] = INFV;
        float tau     = qv ? INFV : -INFV; // invalid groups never enqueue
        float rtau_pw = qv ? INFV : -INFV; // and stop after one group
        int   cnt = 0;
        int   tauLeft = 3;                 // full tau-merges remaining

        // s[] is c-space (c = d2 - q2); tau (c-space, group-shared) gates
        // enqueues; stop radius converts to d2: sqrt(max(tau+q2,0)) + w.
        // tau = exact union-16th at merge time; frozen after 3 merges
        // (stale tau is an upper bound on the final 16th -> exact).
#define DRAIN_ALL() do {                                            \
        drain_batch(s, qb_tid, 0, cnt);                             \
        if (__ballot(cnt > 8)) drain_batch(s, qb_tid, 8, cnt);      \
        cnt = 0;                                                    \
        if (tauLeft > 0) {                                          \
            --tauLeft;                                              \
            float t[16], u[16];                                     \
            _Pragma("unroll")                                       \
            for (int i = 0; i < 16; ++i) t[i] = s[i];               \
            _Pragma("unroll")                                       \
            for (int i = 0; i < 16; ++i) u[i] = __shfl_xor(t[i], 1);\
            _Pragma("unroll")                                       \
            for (int i = 0; i < 16; ++i) t[i] = fminf(t[i], u[15 - i]); \
            bitonic16(t);                                           \
            _Pragma("unroll")                                       \
            for (int i = 0; i < 16; ++i) u[i] = __shfl_xor(t[i], 2);\
            _Pragma("unroll")                                       \
            for (int i = 0; i < 16; ++i) t[i] = fminf(t[i], u[15 - i]); \
            bitonic16(t);                                           \
            _Pragma("unroll")                                       \
            for (int i = 0; i < 16; ++i) u[i] = __shfl_xor(t[i], 4);\
            _Pragma("unroll")                                       \
            for (int i = 0; i < 16; ++i) t[i] = fminf(t[i], u[15 - i]); \
            bitonic16(t);                                           \
            _Pragma("unroll")                                       \
            for (int i = 0; i < 16; ++i) u[i] = __shfl_xor(t[i], 8);\
            _Pragma("unroll")                                       \
            for (int i = 0; i < 16; ++i) t[i] = fminf(t[i], u[15 - i]); \
            float mx = t[0];                                        \
            _Pragma("unroll")                                       \
            for (int i = 1; i < 16; ++i) mx = fmaxf(mx, t[i]);      \
            if (qv) { tau = mx;                                     \
                      rtau_pw = sqrtf(fmaxf(mx + q2, 0.0f)) + w; }  \
        }                                                           \
    } while (0)

        // 8 candidates per lane per group (group covers 128 slots). Guard
        // pads keep all touched addresses in-bounds; p only advances while
        // the lane's act is live (bounds by induction, no stray streaming).
#define PROC8(P, ACT, DIRSGN) do {                                  \
        float4 rr[8];                                               \
        _Pragma("unroll")                                           \
        for (int u = 0; u < 8; ++u)                                 \
            rr[u] = R[(P) + (DIRSGN) * (u * 16)];                   \
        _Pragma("unroll")                                           \
        for (int u = 0; u < 8; ++u) {                               \
            const float dxs = ((DIRSGN) > 0) ? (rr[u].x - qx)       \
                                             : (qx - rr[u].x);      \
            const bool go = (ACT) & (dxs < rtau_pw);                \
            const float cd = fmaf(nx, rr[u].x, fmaf(ny, rr[u].y,    \
                             fmaf(nz, rr[u].z, rr[u].w)));          \
            qbuf[cnt * 64 + tid] = cd;                              \
            cnt += (go & (cd < tau)) ? 1 : 0;                       \
            (ACT) = go;                                             \
        }                                                           \
        (P) += (ACT) ? (DIRSGN) * 128 : 0;                          \
    } while (0)

        int  pr = start + l;
        int  pl = start - 16 + l;
        bool actR = true, actL = true;

        // centered probe: 128 right + 128 left (cnt <= 16 = QDEPTH), then
        // forced full drain -> first tau estimate.
        PROC8(pr, actR, 1);
        PROC8(pl, actL, -1);
        DRAIN_ALL();

        // right phase (continues at start+128)
        while (__ballot(actR)) {
            PROC8(pr, actR, 1);
            if (__ballot(cnt >= QDEPTH - 7)) DRAIN_ALL();
        }
        // left phase (continues at start-144+l); pruned by tau
        while (__ballot(actL)) {
            PROC8(pl, actL, -1);
            if (__ballot(cnt >= QDEPTH - 7)) DRAIN_ALL();
        }
        if (__ballot(cnt > 0)) DRAIN_ALL();

#undef PROC8
#undef DRAIN_ALL

        // group merge (destructive, lists disjoint): after 4 halver rounds
        // all 16 lanes hold the union top-16 multiset; sum is order-free.
        {
            float u[16];
#pragma unroll
            for (int i = 0; i < 16; ++i) u[i] = __shfl_xor(s[i], 1);
#pragma unroll
            for (int i = 0; i < 16; ++i) s[i] = fminf(s[i], u[15 - i]);
            bitonic16(s);
#pragma unroll
            for (int i = 0; i < 16; ++i) u[i] = __shfl_xor(s[i], 2);
#pragma unroll
            for (int i = 0; i < 16; ++i) s[i] = fminf(s[i], u[15 - i]);
            bitonic16(s);
#pragma unroll
            for (int i = 0; i < 16; ++i) u[i] = __shfl_xor(s[i], 4);
#pragma unroll
            for (int i = 0; i < 16; ++i) s[i] = fminf(s[i], u[15 - i]);
            bitonic16(s);
#pragma unroll
            for (int i = 0; i < 16; ++i) u[i] = __shfl_xor(s[i], 8);
#pragma unroll
            for (int i = 0; i < 16; ++i) s[i] = fminf(s[i], u[15 - i]);
        }

        if (qv) {
#pragma unroll
            for (int i = 0; i < 16; ++i)
                accTot += sqrtf(fmaxf(s[i] + q2, 0.0f));  // d2 = c + |q|^2
        }
    }

    // one output atomic per wave
#pragma unroll
    for (int off = 32; off > 0; off >>= 1)
        accTot += __shfl_down(accTot, off);
    if (tid == 0) atomicAdd(out, accTot * scale_out);
}

extern "C" void kernel_launch(void* const* d_in, const int* in_sizes, int n_in,
                              void* d_out, int out_size, void* d_ws, size_t ws_size,
                              hipStream_t stream) {
    const float* src  = (const float*)d_in[0];   // pc_source [B,N,3]
    const float* tgt  = (const float*)d_in[1];   // pc_target [B,M,3]
    const float* flow = (const float*)d_in[2];   // pred_flow [B,N,3]
    float* out = (float*)d_out;

    const int B = 2;                              // per reference setup
    const int N = in_sizes[0] / (B * 3);
    const int M = in_sizes[1] / (B * 3);

    // workspace: ps4 (guarded, sorted) | ts4 | goffs | hdr | ctr
    float4* ps4 = (float4*)d_ws;
    float4* ts4 = ps4 + (size_t)2 * (N + 2 * GUARD);
    int*    goffs = (int*)(ts4 + (size_t)2 * (M + 2 * GUARD));
    float*  hdr = (float*)(goffs + 4 * (NB + 1));   // 4 sets x {xmin,sc,w,pad}
    int*    ctr = (int*)(hdr + 16);                 // 4 chunk-queue counters

    binsort_kernel<<<4, 1024, 0, stream>>>(
        src, tgt, flow, ps4, ts4, goffs, hdr, ctr, out, N, M);

    dim3 grid(1024, 4);                    // persistent 1-wave blocks
    float scale_out = 1.0f / (16.0f * 16.0f * (float)B * (float)N);
    scan_kernel<<<grid, 64, 0, stream>>>(
        ps4, ts4, goffs, hdr, ctr, out, N, M, scale_out);
}

// Round 8
// 162.088 us; speedup vs baseline: 1.4807x; 1.4807x over previous
//
#include <hip/hip_runtime.h>
#include <math.h>

// Chamfer k-NN (k=16, L2), R21: R19 skeleton + register-double-buffered
// candidate stream (software pipeline).
// R20 post-mortem: VALU work identical R19/R20 (7.7e7 wave-inst); R20 only
// halved resident waves (4096 vs 8192) -> VALUBusy 62->37, dur 100->171.
// Per-wave issue fraction ~8% in both => each wave ~92% stalled, mostly
// vmcnt exposure: PROC8 issued 8 loads then consumed rr[0] immediately
// (~250cyc L2 latency vs 128cyc compute per group). Fixes:
//  - 4-candidate half-groups, A/B register double-buffer (load B while
//    processing A). Same 32-VGPR data footprint as old rr[8].
//  - clamped UNCONDITIONAL pointer advance (prefetch addr independent of
//    act); clamps land in the +-1e30/w=INFV guard band (inert).
//  - static 8192-wave mapping with x45 chunk remap (R19), 256-thr blocks.
//  - keep: fused binsort+pack (R20), tauLeft=3, QDEPTH=16, centered probe.
// Pipeline: binsort_fused (4 blocks; zeroes out; per-set counting sort +
// guards + header {xmin,sc,w}) -> scan (two-sided, stop dx>=sqrt(tau_d2)+w).

#define INFV    3.0e38f
#define QDEPTH  16
#define NB      512
#define GUARD   320

__device__ __forceinline__ void ce(float& a, float& b) {
    float lo = fminf(a, b);
    b = fmaxf(a, b);
    a = lo;
}

// bitonic merge-sort of a bitonic 16-seq (stages 8,4,2,1 = 32 CE), ascending
__device__ __forceinline__ void bitonic16(float (&s)[16]) {
    ce(s[0],s[8]);  ce(s[1],s[9]);  ce(s[2],s[10]); ce(s[3],s[11]);
    ce(s[4],s[12]); ce(s[5],s[13]); ce(s[6],s[14]); ce(s[7],s[15]);
    ce(s[0],s[4]);  ce(s[1],s[5]);  ce(s[2],s[6]);  ce(s[3],s[7]);
    ce(s[8],s[12]); ce(s[9],s[13]); ce(s[10],s[14]);ce(s[11],s[15]);
    ce(s[0],s[2]);  ce(s[1],s[3]);  ce(s[4],s[6]);  ce(s[5],s[7]);
    ce(s[8],s[10]); ce(s[9],s[11]); ce(s[12],s[14]);ce(s[13],s[15]);
    ce(s[0],s[1]);  ce(s[2],s[3]);  ce(s[4],s[5]);  ce(s[6],s[7]);
    ce(s[8],s[9]);  ce(s[10],s[11]);ce(s[12],s[13]);ce(s[14],s[15]);
}

// Merge up to 8 queued values (qb[(base+i)*256], i<cnt-base) into sorted s[16].
__device__ __forceinline__ void drain_batch(float (&s)[16], const float* qb,
                                            int base, int cnt)
{
    float q[8];
#pragma unroll
    for (int i = 0; i < 8; ++i) {
        float v = qb[(base + i) * 256];
        q[i] = (base + i < cnt) ? v : INFV;
    }
    // sort8 ascending -- Batcher odd-even, 19 CE
    ce(q[0],q[1]); ce(q[2],q[3]); ce(q[4],q[5]); ce(q[6],q[7]);
    ce(q[0],q[2]); ce(q[1],q[3]); ce(q[4],q[6]); ce(q[5],q[7]);
    ce(q[1],q[2]); ce(q[5],q[6]);
    ce(q[0],q[4]); ce(q[1],q[5]); ce(q[2],q[6]); ce(q[3],q[7]);
    ce(q[2],q[4]); ce(q[3],q[5]);
    ce(q[1],q[2]); ce(q[3],q[4]); ce(q[5],q[6]);
    // bitonic halver vs sorted s[16]
#pragma unroll
    for (int i = 0; i < 8; ++i) s[8 + i] = fminf(s[8 + i], q[7 - i]);
    bitonic16(s);
}

__device__ __forceinline__ int binof(float x, float xmin, float sc) {
    int bn = (int)((x - xmin) * sc);
    return bn < 0 ? 0 : (bn > NB - 1 ? NB - 1 : bn);
}

// Fused pack + counting-sort. blockIdx.x: 0=pred b0, 1=pred b1, 2=tgt b0,
// 3=tgt b1. Per-set x-range found in-block (LDS reduce) -> per-set bins.
// Destination layout per set: [GUARD front | n data | GUARD back].
__global__ __launch_bounds__(1024) void binsort_kernel(
    const float* __restrict__ src, const float* __restrict__ tgt,
    const float* __restrict__ flow,
    float4* __restrict__ ps4, float4* __restrict__ ts4,
    int* __restrict__ goffs, float* __restrict__ hdr,
    float* __restrict__ out, int N, int M)
{
    const int a = blockIdx.x, tid = threadIdx.x;
    const int n = (a < 2) ? N : M;
    const float* P0 = (a < 2) ? src + (size_t)a * N * 3
                              : tgt + (size_t)(a - 2) * M * 3;
    const float* F0 = (a < 2) ? flow + (size_t)a * N * 3 : (const float*)0;
    float4* dst = (a < 2) ? ps4 + (size_t)a * (N + 2 * GUARD)
                          : ts4 + (size_t)(a - 2) * (M + 2 * GUARD);

    if (tid == 0 && a == 0) out[0] = 0.0f;   // replaces memset (poison 0xAA)

    // guard pads: x=+-1e30 kills the act-chain once rtau is finite; w=INFV
    // makes cd round to exactly INFV -> never enqueued even under tau=INFV.
    for (int i = tid; i < GUARD; i += 1024) {
        dst[i] = make_float4(-1e30f, 0.f, 0.f, INFV);
        dst[GUARD + n + i] = make_float4(1e30f, 0.f, 0.f, INFV);
    }

    // per-set x min/max
    float lmin = INFV, lmax = -INFV;
    for (int i = tid; i < n; i += 1024) {
        float x = P0[3 * i];
        if (a < 2) x += F0[3 * i];
        lmin = fminf(lmin, x); lmax = fmaxf(lmax, x);
    }
#pragma unroll
    for (int off = 32; off > 0; off >>= 1) {
        lmin = fminf(lmin, __shfl_down(lmin, off));
        lmax = fmaxf(lmax, __shfl_down(lmax, off));
    }
    __shared__ float rmin[16], rmax[16];
    __shared__ float sxmin, ssc;
    __shared__ int hist[NB];
    __shared__ int offs[NB + 1];
    __shared__ int cur[NB];
    if ((tid & 63) == 0) { rmin[tid >> 6] = lmin; rmax[tid >> 6] = lmax; }
    if (tid < NB) { hist[tid] = 0; cur[tid] = 0; }
    __syncthreads();
    if (tid == 0) {
        float mn = rmin[0], mx = rmax[0];
#pragma unroll
        for (int i = 1; i < 16; ++i) {
            mn = fminf(mn, rmin[i]); mx = fmaxf(mx, rmax[i]);
        }
        float range = mx - mn;
        float sc = (range > 0.f) ? (float)NB / range : 0.f;
        float w  = (range > 0.f) ? range * (1.0f / NB) : INFV;
        sxmin = mn; ssc = sc;
        hdr[a * 4 + 0] = mn; hdr[a * 4 + 1] = sc; hdr[a * 4 + 2] = w;
    }
    __syncthreads();
    const float xmin = sxmin, sc = ssc;

    for (int i = tid; i < n; i += 1024) {
        float x = P0[3 * i];
        if (a < 2) x += F0[3 * i];
        atomicAdd(&hist[binof(x, xmin, sc)], 1);
    }
    __syncthreads();
    // single-wave prefix scan over NB=512 bins
    if (tid < 64) {
        const int base = tid * 8;
        int inc[8];
        int run = 0;
#pragma unroll
        for (int i = 0; i < 8; ++i) { run += hist[base + i]; inc[i] = run; }
        int x = run;
#pragma unroll
        for (int off = 1; off < 64; off <<= 1) {
            int y = __shfl_up(x, off);
            if (tid >= (unsigned)off) x += y;
        }
        const int excl = x - run;
#pragma unroll
        for (int i = 0; i < 8; ++i) offs[base + 1 + i] = excl + inc[i];
        if (tid == 0) offs[0] = 0;
    }
    __syncthreads();
    for (int i = tid; i < n; i += 1024) {
        float x = P0[3 * i], y = P0[3 * i + 1], z = P0[3 * i + 2];
        if (a < 2) { x += F0[3 * i]; y += F0[3 * i + 1]; z += F0[3 * i + 2]; }
        int bn = binof(x, xmin, sc);
        int slot = atomicAdd(&cur[bn], 1);
        dst[GUARD + offs[bn] + slot] =
            make_float4(x, y, z, fmaf(x, x, fmaf(y, y, z * z)));
    }
    if (tid <= NB) goffs[a * (NB + 1) + tid] = offs[tid];
}

// 256 threads = 4 waves; 4 queries/wave, 16 lanes/query (stride 16).
__global__ __launch_bounds__(256, 4) void scan_kernel(
    const float4* __restrict__ ps4, const float4* __restrict__ ts4,
    const int* __restrict__ goffs, const float* __restrict__ hdr,
    float* __restrict__ out, int N, int M, float scale_out)
{
    __shared__ float qbuf[QDEPTH * 256];   // 16 KB per-thread queues, stride 256
    __shared__ float wsum[4];

    const int tid = threadIdx.x;
    const int z = blockIdx.y, b = z >> 1, dir = z & 1;
    const int nq = dir ? M : N;
    const int SN = N + 2 * GUARD, SM = M + 2 * GUARD;
    const float4* Qb = dir ? (ts4 + (size_t)b * SM) : (ps4 + (size_t)b * SN);
    const float4* R  = dir ? (ps4 + (size_t)b * SN) : (ts4 + (size_t)b * SM);
    const int oid = dir ? b : 2 + b;       // set id of the REF array
    const int SR  = dir ? SN : SM;         // guarded length of REF array
    const float xmin = hdr[oid * 4 + 0];
    const float sc   = hdr[oid * 4 + 1];
    const float w    = hdr[oid * 4 + 2];

    // per-wave chunk remap: mix dense/sparse x-regions across CUs
    const int W = gridDim.x * 4;
    const int wv = blockIdx.x * 4 + (tid >> 6);
    const int c = ((W & (W - 1)) == 0) ? ((wv * 45) & (W - 1)) : wv;
    const int qidx = c * 4 + ((tid >> 4) & 3);   // 4 consecutive queries/wave
    const bool qv = qidx < nq;
    const int l = tid & 15;                // lane within 16-lane group

    float4 q = Qb[GUARD + (qv ? qidx : 0)];
    const float qx = q.x, q2 = q.w;
    const float nx = -2.f * q.x, ny = -2.f * q.y, nz = -2.f * q.z;
    const int start = GUARD + goffs[oid * (NB + 1) + binof(qx, xmin, sc)];
    const int clampR = SR - 49;            // base+48 <= SR-1; lands in guard
    const int clampL = 48;                 // base-48 >= 0; lands in guard

    float s[16];
#pragma unroll
    for (int i = 0; i < 16; ++i) s[i] = INFV;
    float tau     = qv ? INFV : -INFV;     // invalid groups never enqueue
    float rtau_pw = qv ? INFV : -INFV;     // and stop after one group
    int   cnt = 0;
    int   tauLeft = 3;                     // full tau-merges remaining
    const float* qb_tid = qbuf + tid;

    // s[] is c-space (c = d2 - q2); tau (c-space, group-shared) gates
    // enqueues; stop radius converts to d2: sqrt(max(tau+q2,0)) + w.
    // tau = exact union-16th at merge time; frozen after 3 merges (stale
    // tau is an upper bound on the final 16th -> pruning exact).
#define DRAIN_ALL() do {                                            \
        drain_batch(s, qb_tid, 0, cnt);                             \
        if (__ballot(cnt > 8)) drain_batch(s, qb_tid, 8, cnt);      \
        cnt = 0;                                                    \
        if (tauLeft > 0) {                                          \
            --tauLeft;                                              \
            float t[16], u[16];                                     \
            _Pragma("unroll")                                       \
            for (int i = 0; i < 16; ++i) t[i] = s[i];               \
            _Pragma("unroll")                                       \
            for (int i = 0; i < 16; ++i) u[i] = __shfl_xor(t[i], 1);\
            _Pragma("unroll")                                       \
            for (int i = 0; i < 16; ++i) t[i] = fminf(t[i], u[15 - i]); \
            bitonic16(t);                                           \
            _Pragma("unroll")                                       \
            for (int i = 0; i < 16; ++i) u[i] = __shfl_xor(t[i], 2);\
            _Pragma("unroll")                                       \
            for (int i = 0; i < 16; ++i) t[i] = fminf(t[i], u[15 - i]); \
            bitonic16(t);                                           \
            _Pragma("unroll")                                       \
            for (int i = 0; i < 16; ++i) u[i] = __shfl_xor(t[i], 4);\
            _Pragma("unroll")                                       \
            for (int i = 0; i < 16; ++i) t[i] = fminf(t[i], u[15 - i]); \
            bitonic16(t);                                           \
            _Pragma("unroll")                                       \
            for (int i = 0; i < 16; ++i) u[i] = __shfl_xor(t[i], 8);\
            _Pragma("unroll")                                       \
            for (int i = 0; i < 16; ++i) t[i] = fminf(t[i], u[15 - i]); \
            float mx = t[0];                                        \
            _Pragma("unroll")                                       \
            for (int i = 1; i < 16; ++i) mx = fmaxf(mx, t[i]);      \
            if (qv) { tau = mx;                                     \
                      rtau_pw = sqrtf(fmaxf(mx + q2, 0.0f)) + w; }  \
        }                                                           \
    } while (0)

#define LOAD4(RR, P, DIRSGN) do {                                   \
        _Pragma("unroll")                                           \
        for (int u = 0; u < 4; ++u)                                 \
            RR[u] = R[(P) + (DIRSGN) * (u * 16)];                   \
    } while (0)

    // process 4 candidates already in registers (half-group = 64 slots)
#define PROC4(RR, ACT, DIRSGN) do {                                 \
        _Pragma("unroll")                                           \
        for (int u = 0; u < 4; ++u) {                               \
            const float dxs = ((DIRSGN) > 0) ? (RR[u].x - qx)       \
                                             : (qx - RR[u].x);      \
            const bool go = (ACT) & (dxs < rtau_pw);                \
            const float cd = fmaf(nx, RR[u].x, fmaf(ny, RR[u].y,    \
                             fmaf(nz, RR[u].z, RR[u].w)));          \
            qbuf[cnt * 256 + tid] = cd;                             \
            cnt += (go & (cd < tau)) ? 1 : 0;                       \
            (ACT) = go;                                             \
        }                                                           \
    } while (0)

    float4 A[4], B[4];
    bool actR = true, actL = true;

    // centered probe: 128 right + 128 left (cnt <= 16 = QDEPTH exactly),
    // then forced full drain -> first tau estimate. All indices in-bounds.
    {
        LOAD4(A, start + l, 1);
        LOAD4(B, start + l + 64, 1);
        PROC4(A, actR, 1);
        PROC4(B, actR, 1);
        LOAD4(A, start - 16 + l, -1);
        LOAD4(B, start - 80 + l, -1);
        PROC4(A, actL, -1);
        PROC4(B, actL, -1);
        DRAIN_ALL();
    }

    // right phase (continues at start+128): A/B double-buffered stream.
    {
        int pA = start + l + 128; if (pA > clampR) pA = clampR;
        int pB = pA + 64;         if (pB > clampR) pB = clampR;
        LOAD4(A, pA, 1);
        LOAD4(B, pB, 1);
        int p = pB;
        while (__ballot(actR)) {
            int pN = p + 64; if (pN > clampR) pN = clampR;
            PROC4(A, actR, 1);                 // B (and A) in flight
            LOAD4(A, pN, 1);                   // prefetch next half-group
            if (__ballot(cnt >= QDEPTH - 3)) DRAIN_ALL();
            int pN2 = pN + 64; if (pN2 > clampR) pN2 = clampR;
            PROC4(B, actR, 1);
            LOAD4(B, pN2, 1);
            if (__ballot(cnt >= QDEPTH - 3)) DRAIN_ALL();
            p = pN2;
        }
    }
    // left phase (continues at start-144+l); pruned by near-final tau.
    {
        int pA = start - 144 + l; if (pA < clampL) pA = clampL;
        int pB = pA - 64;         if (pB < clampL) pB = clampL;
        LOAD4(A, pA, -1);
        LOAD4(B, pB, -1);
        int p = pB;
        while (__ballot(actL)) {
            int pN = p - 64; if (pN < clampL) pN = clampL;
            PROC4(A, actL, -1);
            LOAD4(A, pN, -1);
            if (__ballot(cnt >= QDEPTH - 3)) DRAIN_ALL();
            int pN2 = pN - 64; if (pN2 < clampL) pN2 = clampL;
            PROC4(B, actL, -1);
            LOAD4(B, pN2, -1);
            if (__ballot(cnt >= QDEPTH - 3)) DRAIN_ALL();
            p = pN2;
        }
    }
    if (__ballot(cnt > 0)) DRAIN_ALL();

#undef PROC4
#undef LOAD4
#undef DRAIN_ALL

    // group merge (destructive, lists disjoint): after 4 halver rounds all
    // 16 lanes hold the union top-16 multiset; sum is order-free.
    {
        float u[16];
#pragma unroll
        for (int i = 0; i < 16; ++i) u[i] = __shfl_xor(s[i], 1);
#pragma unroll
        for (int i = 0; i < 16; ++i) s[i] = fminf(s[i], u[15 - i]);
        bitonic16(s);
#pragma unroll
        for (int i = 0; i < 16; ++i) u[i] = __shfl_xor(s[i], 2);
#pragma unroll
        for (int i = 0; i < 16; ++i) s[i] = fminf(s[i], u[15 - i]);
        bitonic16(s);
#pragma unroll
        for (int i = 0; i < 16; ++i) u[i] = __shfl_xor(s[i], 4);
#pragma unroll
        for (int i = 0; i < 16; ++i) s[i] = fminf(s[i], u[15 - i]);
        bitonic16(s);
#pragma unroll
        for (int i = 0; i < 16; ++i) u[i] = __shfl_xor(s[i], 8);
#pragma unroll
        for (int i = 0; i < 16; ++i) s[i] = fminf(s[i], u[15 - i]);
    }

    float acc = 0.0f;
    if (qv) {
#pragma unroll
        for (int i = 0; i < 16; ++i)
            acc += sqrtf(fmaxf(s[i] + q2, 0.0f));   // true d2 = c + |q|^2
    }
#pragma unroll
    for (int off = 32; off > 0; off >>= 1) acc += __shfl_down(acc, off);
    const int lane = tid & 63, wid = tid >> 6;
    if (lane == 0) wsum[wid] = acc;
    __syncthreads();
    if (tid == 0)
        atomicAdd(out, (wsum[0] + wsum[1] + wsum[2] + wsum[3]) * scale_out);
}

extern "C" void kernel_launch(void* const* d_in, const int* in_sizes, int n_in,
                              void* d_out, int out_size, void* d_ws, size_t ws_size,
                              hipStream_t stream) {
    const float* src  = (const float*)d_in[0];   // pc_source [B,N,3]
    const float* tgt  = (const float*)d_in[1];   // pc_target [B,M,3]
    const float* flow = (const float*)d_in[2];   // pred_flow [B,N,3]
    float* out = (float*)d_out;

    const int B = 2;                              // per reference setup
    const int N = in_sizes[0] / (B * 3);
    const int M = in_sizes[1] / (B * 3);

    // workspace: ps4 (guarded, sorted) | ts4 | goffs | hdr
    float4* ps4 = (float4*)d_ws;
    float4* ts4 = ps4 + (size_t)2 * (N + 2 * GUARD);
    int*    goffs = (int*)(ts4 + (size_t)2 * (M + 2 * GUARD));
    float*  hdr = (float*)(goffs + 4 * (NB + 1));   // 4 sets x {xmin,sc,w,pad}

    binsort_kernel<<<4, 1024, 0, stream>>>(
        src, tgt, flow, ps4, ts4, goffs, hdr, out, N, M);

    int maxq = (N > M) ? N : M;
    dim3 grid((maxq + 15) / 16, 2 * B);   // 16 queries per 256-thr block
    float scale_out = 1.0f / (16.0f * 16.0f * (float)B * (float)N);
    scan_kernel<<<grid, 256, 0, stream>>>(
        ps4, ts4, goffs, hdr, out, N, M, scale_out);
}